// Round 4
// baseline (504.765 us; speedup 1.0000x reference)
//
#include <hip/hip_runtime.h>
#include <hip/hip_bf16.h>

// Problem constants
#define NB 2
#define NN 512
#define HH 128
#define DD 128
#define TT 8

// ws layout (bytes).
#define WPACK_OFF 0        // ushort[16*144*8] = 36864 B, bf16 [k/8][n][k%8]
#define C_OFF     36864    // float[2*512*128]  z@Wm1 + g@Wmg + (bm1+bm2+bme+bmg)
#define BROW_OFF  561152   // float[2*512*128]  z@Wm2
#define TC_OFF    1085440  // float[2*512*8]    z@Wt1 + g@Wtg + (bt1+bt2+bte+btg)
#define TB_OFF    1118208  // float[2*512*8]    z@Wt2
#define OC_OFF    1150976  // float[2*512*128]  z@Wo1 + bo1 + bo2
#define PART_OFF  1675264  // float[2*8*512*128] partial max (no C) per 64-sender chunk
#define ZF_OFF    18452480 // int[2*8*512]      1 if any sender in chunk has adj==0

#define OUT_TRI   131072   // float offset of tri_msgs in d_out

typedef float f32x4 __attribute__((ext_vector_type(4)));
typedef short s16x8 __attribute__((ext_vector_type(8)));

__device__ __forceinline__ unsigned short f2bf(float f) {
    union { float f; unsigned int u; } x; x.f = f;
    unsigned int u = x.u;
    unsigned int r = (u + 0x7FFFu + ((u >> 16) & 1u)) >> 16;  // RNE
    return (unsigned short)r;
}

// packed f32x2 -> bf16x2 (RNE). HW instr v_cvt_pk_bf16_f32 when available.
__device__ __forceinline__ unsigned cvt2bf(float a, float b) {
#if __has_builtin(__builtin_amdgcn_cvt_pk_bf16_f32)
    auto r = __builtin_amdgcn_cvt_pk_bf16_f32(a, b);
    return __builtin_bit_cast(unsigned, r);
#else
    return (unsigned)f2bf(a) | ((unsigned)f2bf(b) << 16);
#endif
}

// ---------------------------------------------------------------------------
// k0: precompute small projections (fp32) + pack bf16 weights for MFMA
// ---------------------------------------------------------------------------
__global__ __launch_bounds__(256) void k0_precompute(
    const float* __restrict__ node, const float* __restrict__ hidden,
    const float* __restrict__ graph,
    const float* __restrict__ Wm1, const float* __restrict__ Wm2,
    const float* __restrict__ Wo1, const float* __restrict__ Wmg,
    const float* __restrict__ Wt1, const float* __restrict__ Wt2,
    const float* __restrict__ Wtg,
    const float* __restrict__ Wme, const float* __restrict__ Wte,
    const float* __restrict__ bm1, const float* __restrict__ bm2,
    const float* __restrict__ bme, const float* __restrict__ bmg,
    const float* __restrict__ bo1, const float* __restrict__ bo2,
    const float* __restrict__ bt1, const float* __restrict__ bt2,
    const float* __restrict__ bte, const float* __restrict__ btg,
    char* __restrict__ ws)
{
    const int bx = blockIdx.x, tid = threadIdx.x;
    if (bx == 256) {
        unsigned short* wp = (unsigned short*)(ws + WPACK_OFF);
        for (int idx = tid; idx < 16 * 144 * 8; idx += 256) {
            int j = idx & 7, tmp = idx >> 3;
            int n = tmp % 144, kq = tmp / 144;
            int k = kq * 8 + j;
            float v = 0.f;
            if (n < 128) v = Wme[k * 128 + n];
            else if (n < 136) v = Wte[k * 8 + (n - 128)];
            wp[idx] = f2bf(v);
        }
        return;
    }
    __shared__ float zs[4 * 257];
    const int row0 = bx * 4;
    const int b = row0 >> 9;
    #pragma unroll
    for (int e = 0; e < 4; e++) {
        int idx = e * 256 + tid;
        int rl = idx >> 8, col = idx & 255;
        float v = (col < 128) ? node[(row0 + rl) * 128 + col]
                              : hidden[(row0 + rl) * 128 + col - 128];
        zs[rl * 257 + col] = v;
    }
    __syncthreads();

    float* Cws = (float*)(ws + C_OFF);
    float* Bws = (float*)(ws + BROW_OFF);
    float* Ows = (float*)(ws + OC_OFF);
    float* TCw = (float*)(ws + TC_OFF);
    float* TBw = (float*)(ws + TB_OFF);

    const int d = tid & 127, half = tid >> 7;
    const float* z0 = zs + (half * 2) * 257;
    const float* z1 = zs + (half * 2 + 1) * 257;
    float c0 = 0.f, c1 = 0.f, q0 = 0.f, q1 = 0.f, o0 = 0.f, o1 = 0.f;
    for (int k = 0; k < 256; k++) {
        float w1 = Wm1[k * 128 + d], w2 = Wm2[k * 128 + d], wo = Wo1[k * 128 + d];
        float za = z0[k], zb = z1[k];
        c0 += za * w1; c1 += zb * w1;
        q0 += za * w2; q1 += zb * w2;
        o0 += za * wo; o1 += zb * wo;
    }
    float gm = 0.f;
    for (int k = 0; k < 128; k++) gm += graph[b * 128 + k] * Wmg[k * 128 + d];
    const float cb = gm + bm1[d] + bm2[d] + bme[d] + bmg[d];
    const float ob = bo1[d] + bo2[d];
    const int r0 = row0 + half * 2;
    Cws[r0 * 128 + d] = c0 + cb;  Cws[(r0 + 1) * 128 + d] = c1 + cb;
    Bws[r0 * 128 + d] = q0;       Bws[(r0 + 1) * 128 + d] = q1;
    Ows[r0 * 128 + d] = o0 + ob;  Ows[(r0 + 1) * 128 + d] = o1 + ob;

    if (tid < 64) {
        int r4 = tid >> 4, t = (tid >> 1) & 7, which = tid & 1;
        const float* zr = zs + r4 * 257;
        const float* W = which ? Wt2 : Wt1;
        float acc = 0.f;
        for (int k = 0; k < 256; k++) acc += zr[k] * W[k * 8 + t];
        int rg = row0 + r4;
        if (which == 0) {
            float gt = 0.f;
            for (int k = 0; k < 128; k++) gt += graph[b * 128 + k] * Wtg[k * 8 + t];
            TCw[rg * 8 + t] = acc + gt + bt1[t] + bt2[t] + bte[t] + btg[t];
        } else {
            TBw[rg * 8 + t] = acc;
        }
    }
}

// ---------------------------------------------------------------------------
// k2: fused edge GEMM + tri + masked max. B register-resident; A loads
// depth-1 software-prefetched; packed bf16 cvt; no mid-loop barriers.
// grid (32 jt, 8 ic, 2 b) = 512 blocks x 512 thr (8 waves = 2 g x 4 sq).
// ---------------------------------------------------------------------------
__global__ __launch_bounds__(512, 2) void k2_main(
    const float* __restrict__ edge, const float* __restrict__ adj,
    char* __restrict__ ws, float* __restrict__ out)
{
    __shared__ float red[8][16][64];   // 32 KB: per-wave Mx dump
    __shared__ int zflag[16];
    const int tid = threadIdx.x;
    const int jt = blockIdx.x, ic = blockIdx.y, b = blockIdx.z;
    const int j0 = jt * 16, i0 = ic * 64;

    const int lane = tid & 63, wave = tid >> 6;
    const int g = wave >> 2, sq = wave & 3;
    const int quad = lane >> 4, l15 = lane & 15;
    const int ntbase = g * 4;

    if (tid < 16) zflag[tid] = 0;
    __syncthreads();

    const float* Bws = (const float*)(ws + BROW_OFF);
    const float* TCw = (const float*)(ws + TC_OFF);
    const float* TBw = (const float*)(ws + TB_OFF);
    const s16x8* wp8 = (const s16x8*)(ws + WPACK_OFF);
    float* part = (float*)(ws + PART_OFF);
    int* Zws = (int*)(ws + ZF_OFF);

    // B fragments -> registers (loop-invariant). 5 tiles x 4 k-steps.
    s16x8 Bf[5][4];
    #pragma unroll
    for (int s = 0; s < 4; s++) {
        #pragma unroll
        for (int ntl = 0; ntl < 5; ntl++) {
            int nt = (ntl < 4) ? (ntbase + ntl) : 8;
            Bf[ntl][s] = wp8[(4 * s + quad) * 144 + nt * 16 + l15];
        }
    }

    const int jb = j0 + quad * 4;
    float TCf[4];
    #pragma unroll
    for (int r = 0; r < 4; r++)
        TCf[r] = (l15 < 8) ? TCw[(b * 512 + jb + r) * 8 + l15] : 0.f;

    float Mx[4][4];
    #pragma unroll
    for (int ntl = 0; ntl < 4; ntl++)
        #pragma unroll
        for (int r = 0; r < 4; r++) Mx[ntl][r] = -INFINITY;
    int anyz[4] = {0, 0, 0, 0};

    // A row base for this wave's first sender; +65536 floats per sender.
    const int ig0 = i0 + sq * 16;
    const float* erow = edge + ((b * 512 + ig0) * 512 + j0 + l15) * 128 + quad * 8;

    // prefetch iter 0's raw A
    float4 raw[8];
    #pragma unroll
    for (int s = 0; s < 4; s++) {
        raw[2 * s]     = *(const float4*)(erow + s * 32);
        raw[2 * s + 1] = *(const float4*)(erow + s * 32 + 4);
    }

    for (int ii = 0; ii < 16; ii++) {
        const int ig = ig0 + ii;
        // convert current raw -> af (waits on the prefetched loads)
        s16x8 af[4];
        #pragma unroll
        for (int s = 0; s < 4; s++) {
            union { s16x8 v; unsigned u[4]; } pk;
            float4 p = raw[2 * s], q = raw[2 * s + 1];
            pk.u[0] = cvt2bf(p.x, p.y);
            pk.u[1] = cvt2bf(p.z, p.w);
            pk.u[2] = cvt2bf(q.x, q.y);
            pk.u[3] = cvt2bf(q.z, q.w);
            af[s] = pk.v;
        }
        // issue next iter's A loads (overlap with MFMA + epilogue below)
        if (ii < 15) {
            const float* ernx = erow + (ii + 1) * 65536;
            #pragma unroll
            for (int s = 0; s < 4; s++) {
                raw[2 * s]     = *(const float4*)(ernx + s * 32);
                raw[2 * s + 1] = *(const float4*)(ernx + s * 32 + 4);
            }
        }
        // small per-sender operands (L2-resident)
        float adjv[4];
        const int arow = (b * 512 + ig) * 512 + jb;
        #pragma unroll
        for (int r = 0; r < 4; r++) adjv[r] = adj[arow + r];
        float brw[4];
        const int br0 = (b * 512 + ig) * 128;
        #pragma unroll
        for (int ntl = 0; ntl < 4; ntl++)
            brw[ntl] = Bws[br0 + (ntbase + ntl) * 16 + l15];
        const float tb = (l15 < 8) ? TBw[(b * 512 + ig) * 8 + l15] : 0.f;

        f32x4 acc[5];
        #pragma unroll
        for (int ntl = 0; ntl < 5; ntl++) acc[ntl] = (f32x4){0.f, 0.f, 0.f, 0.f};
        #pragma unroll
        for (int s = 0; s < 4; s++) {
            #pragma unroll
            for (int ntl = 0; ntl < 5; ntl++)
                acc[ntl] = __builtin_amdgcn_mfma_f32_16x16x32_bf16(
                    af[s], Bf[ntl][s], acc[ntl], 0, 0, 0);
        }
        // masked-max epilogue (C deferred to k3)
        #pragma unroll
        for (int r = 0; r < 4; r++) {
            const int isz = (adjv[r] == 0.f);
            anyz[r] |= isz;
            #pragma unroll
            for (int ntl = 0; ntl < 4; ntl++) {
                float v = isz ? -INFINITY : (acc[ntl][r] + brw[ntl]);
                Mx[ntl][r] = fmaxf(Mx[ntl][r], v);
            }
        }
        // tri relu-store (only g==1 stores; both compute for uniformity)
        if (g == 1 && l15 < 8) {
            float* tout = out + OUT_TRI + ((b * 512 + ig) * 512 + jb) * 8 + l15;
            #pragma unroll
            for (int r = 0; r < 4; r++) {
                float tv = acc[4][r] + TCf[r] + tb;
                tout[r * 8] = fmaxf(tv, 0.f);
            }
        }
    }

    // flags + Mx dump
    if (g == 0 && l15 == 0) {
        #pragma unroll
        for (int r = 0; r < 4; r++)
            if (anyz[r]) atomicOr(&zflag[quad * 4 + r], 1);
    }
    #pragma unroll
    for (int ntl = 0; ntl < 4; ntl++)
        #pragma unroll
        for (int r = 0; r < 4; r++)
            red[wave][quad * 4 + r][ntl * 16 + l15] = Mx[ntl][r];
    __syncthreads();

    // final reduce over 4 sender-subsets -> partial[b][ic][j][d]
    {
        const int q = tid;               // one float4 per thread, 512 total
        const int j = q >> 5, dq = q & 31;
        const int g2 = dq >> 4, c0 = (dq & 15) * 4;
        const float* r0p = &red[g2 * 4][j][c0];
        float4 m = *(const float4*)r0p;
        #pragma unroll
        for (int w = 1; w < 4; w++) {
            const float4 o = *(const float4*)&red[g2 * 4 + w][j][c0];
            m.x = fmaxf(m.x, o.x); m.y = fmaxf(m.y, o.y);
            m.z = fmaxf(m.z, o.z); m.w = fmaxf(m.w, o.w);
        }
        *(float4*)(part + ((b * 8 + ic) * 512 + j0 + j) * 128 + dq * 4) = m;
    }
    if (tid < 16) Zws[(b * 8 + ic) * 512 + j0 + tid] = zflag[tid];
}

// ---------------------------------------------------------------------------
// k3: msgs = max(max_ic partial + C, anyzero?0:-inf); ret = Oc + msgs @ Wo2
// ---------------------------------------------------------------------------
__global__ __launch_bounds__(128) void k3_final(
    const char* __restrict__ ws, const float* __restrict__ Wo2,
    float* __restrict__ out)
{
    __shared__ float ms[128];
    const int bj = blockIdx.x, d = threadIdx.x;
    const int b = bj >> 9, j = bj & 511;
    const float* part = (const float*)(ws + PART_OFF);
    const int* Zws = (const int*)(ws + ZF_OFF);
    const float* Cws = (const float*)(ws + C_OFF);
    const float* Ows = (const float*)(ws + OC_OFF);

    const int rj = b * 512 + j;
    float m = -INFINITY;
    int zf = 0;
    #pragma unroll
    for (int ic = 0; ic < 8; ic++) {
        m = fmaxf(m, part[((b * 8 + ic) * 512 + j) * 128 + d]);
        zf |= Zws[(b * 8 + ic) * 512 + j];
    }
    float c = Cws[rj * 128 + d];
    float mm = fmaxf(m + c, zf ? 0.f : -INFINITY);
    ms[d] = mm;
    __syncthreads();
    float acc = Ows[rj * 128 + d];
    #pragma unroll 8
    for (int k = 0; k < 128; k++) acc += ms[k] * Wo2[k * 128 + d];
    out[rj * 128 + d] = acc;
}

extern "C" void kernel_launch(void* const* d_in, const int* in_sizes, int n_in,
                              void* d_out, int out_size, void* d_ws, size_t ws_size,
                              hipStream_t stream) {
    const float* node   = (const float*)d_in[0];
    const float* edge   = (const float*)d_in[1];
    const float* graph  = (const float*)d_in[2];
    const float* adj    = (const float*)d_in[3];
    const float* hidden = (const float*)d_in[4];
    const float* Wm1 = (const float*)d_in[5];  const float* bm1 = (const float*)d_in[6];
    const float* Wm2 = (const float*)d_in[7];  const float* bm2 = (const float*)d_in[8];
    const float* Wme = (const float*)d_in[9];  const float* bme = (const float*)d_in[10];
    const float* Wmg = (const float*)d_in[11]; const float* bmg = (const float*)d_in[12];
    const float* Wo1 = (const float*)d_in[13]; const float* bo1 = (const float*)d_in[14];
    const float* Wo2 = (const float*)d_in[15]; const float* bo2 = (const float*)d_in[16];
    const float* Wt1 = (const float*)d_in[17]; const float* bt1 = (const float*)d_in[18];
    const float* Wt2 = (const float*)d_in[19]; const float* bt2 = (const float*)d_in[20];
    const float* Wte = (const float*)d_in[21]; const float* bte = (const float*)d_in[22];
    const float* Wtg = (const float*)d_in[23]; const float* btg = (const float*)d_in[24];
    float* out = (float*)d_out;
    char* ws = (char*)d_ws;

    k0_precompute<<<dim3(257), dim3(256), 0, stream>>>(
        node, hidden, graph, Wm1, Wm2, Wo1, Wmg, Wt1, Wt2, Wtg, Wme, Wte,
        bm1, bm2, bme, bmg, bo1, bo2, bt1, bt2, bte, btg, ws);
    k2_main<<<dim3(32, 8, 2), dim3(512), 0, stream>>>(edge, adj, ws, out);
    k3_final<<<dim3(1024), dim3(128), 0, stream>>>(ws, Wo2, out);
}

// Round 5
// 500.747 us; speedup vs baseline: 1.0080x; 1.0080x over previous
//
#include <hip/hip_runtime.h>
#include <hip/hip_bf16.h>

// Problem constants
#define NB 2
#define NN 512
#define HH 128
#define DD 128
#define TT 8

// ws layout (bytes).
#define WPACK_OFF 0        // ushort[16*144*8] = 36864 B, bf16 [k/8][n][k%8]
#define C_OFF     36864    // float[2*512*128]  z@Wm1 + g@Wmg + (bm1+bm2+bme+bmg)
#define BROW_OFF  561152   // float[2*512*128]  z@Wm2
#define TC_OFF    1085440  // float[2*512*8]    z@Wt1 + g@Wtg + (bt1+bt2+bte+btg)
#define TB_OFF    1118208  // float[2*512*8]    z@Wt2
#define OC_OFF    1150976  // float[2*512*128]  z@Wo1 + bo1 + bo2
#define PART_OFF  1675264  // float[2*8*512*128] partial max (no C) per 64-sender chunk
#define ZF_OFF    18452480 // int[2*8*512]      1 if any sender in chunk has adj==0

#define OUT_TRI   131072   // float offset of tri_msgs in d_out

typedef float f32x4 __attribute__((ext_vector_type(4)));
typedef short s16x8 __attribute__((ext_vector_type(8)));

__device__ __forceinline__ unsigned short f2bf(float f) {
    union { float f; unsigned int u; } x; x.f = f;
    unsigned int u = x.u;
    unsigned int r = (u + 0x7FFFu + ((u >> 16) & 1u)) >> 16;  // RNE
    return (unsigned short)r;
}

// packed f32x2 -> bf16x2 (RNE). HW instr v_cvt_pk_bf16_f32 when available.
__device__ __forceinline__ unsigned cvt2bf(float a, float b) {
#if __has_builtin(__builtin_amdgcn_cvt_pk_bf16_f32)
    auto r = __builtin_amdgcn_cvt_pk_bf16_f32(a, b);
    return __builtin_bit_cast(unsigned, r);
#else
    return (unsigned)f2bf(a) | ((unsigned)f2bf(b) << 16);
#endif
}

// ---------------------------------------------------------------------------
// k0: precompute small projections (fp32) + pack bf16 weights for MFMA
// grid 513 x 256: blocks 0..511 handle 2 rows each (2 blocks/CU); 512 packs.
// All dot loops unroll-8 so ~24 loads stay in flight per thread.
// ---------------------------------------------------------------------------
__global__ __launch_bounds__(256) void k0_precompute(
    const float* __restrict__ node, const float* __restrict__ hidden,
    const float* __restrict__ graph,
    const float* __restrict__ Wm1, const float* __restrict__ Wm2,
    const float* __restrict__ Wo1, const float* __restrict__ Wmg,
    const float* __restrict__ Wt1, const float* __restrict__ Wt2,
    const float* __restrict__ Wtg,
    const float* __restrict__ Wme, const float* __restrict__ Wte,
    const float* __restrict__ bm1, const float* __restrict__ bm2,
    const float* __restrict__ bme, const float* __restrict__ bmg,
    const float* __restrict__ bo1, const float* __restrict__ bo2,
    const float* __restrict__ bt1, const float* __restrict__ bt2,
    const float* __restrict__ bte, const float* __restrict__ btg,
    char* __restrict__ ws)
{
    const int bx = blockIdx.x, tid = threadIdx.x;
    if (bx == 512) {
        unsigned short* wp = (unsigned short*)(ws + WPACK_OFF);
        for (int idx = tid; idx < 16 * 144 * 8; idx += 256) {
            int j = idx & 7, tmp = idx >> 3;
            int n = tmp % 144, kq = tmp / 144;
            int k = kq * 8 + j;
            float v = 0.f;
            if (n < 128) v = Wme[k * 128 + n];
            else if (n < 136) v = Wte[k * 8 + (n - 128)];
            wp[idx] = f2bf(v);
        }
        return;
    }
    __shared__ float zs[2 * 260];
    const int row0 = bx * 2;       // flat row = b*512 + n
    const int b = row0 >> 9;
    #pragma unroll
    for (int e = 0; e < 2; e++) {
        int idx = e * 256 + tid;
        int rl = idx >> 8, col = idx & 255;
        float v = (col < 128) ? node[(row0 + rl) * 128 + col]
                              : hidden[(row0 + rl) * 128 + col - 128];
        zs[rl * 260 + col] = v;
    }
    __syncthreads();

    float* Cws = (float*)(ws + C_OFF);
    float* Bws = (float*)(ws + BROW_OFF);
    float* Ows = (float*)(ws + OC_OFF);
    float* TCw = (float*)(ws + TC_OFF);
    float* TBw = (float*)(ws + TB_OFF);

    const int d = tid & 127, half = tid >> 7;
    const int row = row0 + half;
    const float* z = zs + half * 260;
    float c = 0.f, q = 0.f, o = 0.f;
    #pragma unroll 8
    for (int k = 0; k < 256; k++) {
        float za = z[k];
        c = fmaf(za, Wm1[k * 128 + d], c);
        q = fmaf(za, Wm2[k * 128 + d], q);
        o = fmaf(za, Wo1[k * 128 + d], o);
    }
    float gm = 0.f;
    #pragma unroll 8
    for (int k = 0; k < 128; k++) gm = fmaf(graph[b * 128 + k], Wmg[k * 128 + d], gm);
    const float cb = gm + bm1[d] + bm2[d] + bme[d] + bmg[d];
    Cws[row * 128 + d] = c + cb;
    Bws[row * 128 + d] = q;
    Ows[row * 128 + d] = o + bo1[d] + bo2[d];

    // triplet projections: 2 rows x 8 t x {TC,TB} = 32 dots
    if (tid < 32) {
        int rl = tid >> 4, t = (tid >> 1) & 7, which = tid & 1;
        const float* zr = zs + rl * 260;
        const float* W = which ? Wt2 : Wt1;
        float acc = 0.f;
        #pragma unroll 8
        for (int k = 0; k < 256; k++) acc = fmaf(zr[k], W[k * 8 + t], acc);
        int rg = row0 + rl;
        if (which == 0) {
            float gt = 0.f;
            #pragma unroll 8
            for (int k = 0; k < 128; k++) gt = fmaf(graph[b * 128 + k], Wtg[k * 8 + t], gt);
            TCw[rg * 8 + t] = acc + gt + bt1[t] + bt2[t] + bte[t] + btg[t];
        } else {
            TBw[rg * 8 + t] = acc;
        }
    }
}

// ---------------------------------------------------------------------------
// k2: fused edge GEMM + tri + masked max. B register-resident.
// Depth-1 ping-pong prefetch of ALL per-iter loads (A + adj + brw + tb),
// issued before any consumer — keeps vmcnt order monotone so the A prefetch
// survives a full iteration (r4's bug: current-iter small loads issued AFTER
// the A prefetch forced vmcnt(0)-equivalent drains every iteration).
// grid (32 jt, 8 ic, 2 b) = 512 blocks x 512 thr (8 waves = 2 g x 4 sq).
// ---------------------------------------------------------------------------
__global__ __launch_bounds__(512, 2) void k2_main(
    const float* __restrict__ edge, const float* __restrict__ adj,
    char* __restrict__ ws, float* __restrict__ out)
{
    __shared__ float red[8][16][64];   // 32 KB: per-wave Mx dump
    __shared__ int zflag[16];
    const int tid = threadIdx.x;
    const int jt = blockIdx.x, ic = blockIdx.y, b = blockIdx.z;
    const int j0 = jt * 16, i0 = ic * 64;

    const int lane = tid & 63, wave = tid >> 6;
    const int g = wave >> 2, sq = wave & 3;
    const int quad = lane >> 4, l15 = lane & 15;
    const int ntbase = g * 4;

    if (tid < 16) zflag[tid] = 0;
    __syncthreads();

    const float* Bws = (const float*)(ws + BROW_OFF);
    const float* TCw = (const float*)(ws + TC_OFF);
    const float* TBw = (const float*)(ws + TB_OFF);
    const s16x8* wp8 = (const s16x8*)(ws + WPACK_OFF);
    float* part = (float*)(ws + PART_OFF);
    int* Zws = (int*)(ws + ZF_OFF);

    // B fragments -> registers (loop-invariant). 5 tiles x 4 k-steps.
    s16x8 Bf[5][4];
    #pragma unroll
    for (int s = 0; s < 4; s++) {
        #pragma unroll
        for (int ntl = 0; ntl < 5; ntl++) {
            int nt = (ntl < 4) ? (ntbase + ntl) : 8;
            Bf[ntl][s] = wp8[(4 * s + quad) * 144 + nt * 16 + l15];
        }
    }

    const int jb = j0 + quad * 4;
    float TCf[4];
    #pragma unroll
    for (int r = 0; r < 4; r++)
        TCf[r] = (l15 < 8) ? TCw[(b * 512 + jb + r) * 8 + l15] : 0.f;

    float Mx[4][4];
    #pragma unroll
    for (int ntl = 0; ntl < 4; ntl++)
        #pragma unroll
        for (int r = 0; r < 4; r++) Mx[ntl][r] = -INFINITY;
    int anyz[4] = {0, 0, 0, 0};

    const int ig0 = i0 + sq * 16;
    const float* erow = edge + ((b * 512 + ig0) * 512 + j0 + l15) * 128 + quad * 8;

    // ping-pong prefetch state
    float4 raw[2][8];
    float4 adjn[2];
    float brwn[2][4];
    float tbn[2];

    // prologue: everything for iter 0 -> set 0
    {
        #pragma unroll
        for (int s = 0; s < 4; s++) {
            raw[0][2 * s]     = *(const float4*)(erow + s * 32);
            raw[0][2 * s + 1] = *(const float4*)(erow + s * 32 + 4);
        }
        adjn[0] = *(const float4*)(adj + (b * 512 + ig0) * 512 + jb);
        const int br0 = (b * 512 + ig0) * 128;
        #pragma unroll
        for (int ntl = 0; ntl < 4; ntl++)
            brwn[0][ntl] = Bws[br0 + (ntbase + ntl) * 16 + l15];
        tbn[0] = (l15 < 8) ? TBw[(b * 512 + ig0) * 8 + l15] : 0.f;
    }

    #pragma unroll 2
    for (int ii = 0; ii < 16; ii++) {
        const int p = ii & 1, pn = p ^ 1;
        const int ig = ig0 + ii;

        // convert current A (waits only on A(ii); smalls(ii) are older, done)
        s16x8 af[4];
        #pragma unroll
        for (int s = 0; s < 4; s++) {
            union { s16x8 v; unsigned u[4]; } pk;
            float4 pv = raw[p][2 * s], qv = raw[p][2 * s + 1];
            pk.u[0] = cvt2bf(pv.x, pv.y);
            pk.u[1] = cvt2bf(pv.z, pv.w);
            pk.u[2] = cvt2bf(qv.x, qv.y);
            pk.u[3] = cvt2bf(qv.z, qv.w);
            af[s] = pk.v;
        }

        // prefetch EVERYTHING for iter ii+1 (issued before any consumer below)
        if (ii < 15) {
            const float* ernx = erow + (ii + 1) * 65536;
            #pragma unroll
            for (int s = 0; s < 4; s++) {
                raw[pn][2 * s]     = *(const float4*)(ernx + s * 32);
                raw[pn][2 * s + 1] = *(const float4*)(ernx + s * 32 + 4);
            }
            const int ign = ig + 1;
            adjn[pn] = *(const float4*)(adj + (b * 512 + ign) * 512 + jb);
            const int brn = (b * 512 + ign) * 128;
            #pragma unroll
            for (int ntl = 0; ntl < 4; ntl++)
                brwn[pn][ntl] = Bws[brn + (ntbase + ntl) * 16 + l15];
            tbn[pn] = (l15 < 8) ? TBw[(b * 512 + ign) * 8 + l15] : 0.f;
        }

        // MFMA
        f32x4 acc[5];
        #pragma unroll
        for (int ntl = 0; ntl < 5; ntl++) acc[ntl] = (f32x4){0.f, 0.f, 0.f, 0.f};
        #pragma unroll
        for (int s = 0; s < 4; s++) {
            #pragma unroll
            for (int ntl = 0; ntl < 5; ntl++)
                acc[ntl] = __builtin_amdgcn_mfma_f32_16x16x32_bf16(
                    af[s], Bf[ntl][s], acc[ntl], 0, 0, 0);
        }

        // masked-max epilogue (C deferred to k3) — uses set p (older than A(ii+2))
        const float av[4] = {adjn[p].x, adjn[p].y, adjn[p].z, adjn[p].w};
        #pragma unroll
        for (int r = 0; r < 4; r++) {
            const int isz = (av[r] == 0.f);
            anyz[r] |= isz;
            #pragma unroll
            for (int ntl = 0; ntl < 4; ntl++) {
                float v = isz ? -INFINITY : (acc[ntl][r] + brwn[p][ntl]);
                Mx[ntl][r] = fmaxf(Mx[ntl][r], v);
            }
        }
        // tri relu-store (only g==1 stores; both compute for uniformity)
        if (g == 1 && l15 < 8) {
            float* tout = out + OUT_TRI + ((b * 512 + ig) * 512 + jb) * 8 + l15;
            #pragma unroll
            for (int r = 0; r < 4; r++) {
                float tv = acc[4][r] + TCf[r] + tbn[p];
                tout[r * 8] = fmaxf(tv, 0.f);
            }
        }
    }

    // flags + Mx dump
    if (g == 0 && l15 == 0) {
        #pragma unroll
        for (int r = 0; r < 4; r++)
            if (anyz[r]) atomicOr(&zflag[quad * 4 + r], 1);
    }
    #pragma unroll
    for (int ntl = 0; ntl < 4; ntl++)
        #pragma unroll
        for (int r = 0; r < 4; r++)
            red[wave][quad * 4 + r][ntl * 16 + l15] = Mx[ntl][r];
    __syncthreads();

    // final reduce over 4 sender-subsets -> partial[b][ic][j][d]
    {
        const int q = tid;               // one float4 per thread, 512 total
        const int j = q >> 5, dq = q & 31;
        const int g2 = dq >> 4, c0 = (dq & 15) * 4;
        const float* r0p = &red[g2 * 4][j][c0];
        float4 m = *(const float4*)r0p;
        #pragma unroll
        for (int w = 1; w < 4; w++) {
            const float4 o = *(const float4*)&red[g2 * 4 + w][j][c0];
            m.x = fmaxf(m.x, o.x); m.y = fmaxf(m.y, o.y);
            m.z = fmaxf(m.z, o.z); m.w = fmaxf(m.w, o.w);
        }
        *(float4*)(part + ((b * 8 + ic) * 512 + j0 + j) * 128 + dq * 4) = m;
    }
    if (tid < 16) Zws[(b * 8 + ic) * 512 + j0 + tid] = zflag[tid];
}

// ---------------------------------------------------------------------------
// k3: msgs = max(max_ic partial + C, anyzero?0:-inf); ret = Oc + msgs @ Wo2
// ---------------------------------------------------------------------------
__global__ __launch_bounds__(128) void k3_final(
    const char* __restrict__ ws, const float* __restrict__ Wo2,
    float* __restrict__ out)
{
    __shared__ float ms[128];
    const int bj = blockIdx.x, d = threadIdx.x;
    const int b = bj >> 9, j = bj & 511;
    const float* part = (const float*)(ws + PART_OFF);
    const int* Zws = (const int*)(ws + ZF_OFF);
    const float* Cws = (const float*)(ws + C_OFF);
    const float* Ows = (const float*)(ws + OC_OFF);

    const int rj = b * 512 + j;
    float m = -INFINITY;
    int zf = 0;
    #pragma unroll
    for (int ic = 0; ic < 8; ic++) {
        m = fmaxf(m, part[((b * 8 + ic) * 512 + j) * 128 + d]);
        zf |= Zws[(b * 8 + ic) * 512 + j];
    }
    float c = Cws[rj * 128 + d];
    float mm = fmaxf(m + c, zf ? 0.f : -INFINITY);
    ms[d] = mm;
    __syncthreads();
    float acc = Ows[rj * 128 + d];
    #pragma unroll 8
    for (int k = 0; k < 128; k++) acc = fmaf(ms[k], Wo2[k * 128 + d], acc);
    out[rj * 128 + d] = acc;
}

extern "C" void kernel_launch(void* const* d_in, const int* in_sizes, int n_in,
                              void* d_out, int out_size, void* d_ws, size_t ws_size,
                              hipStream_t stream) {
    const float* node   = (const float*)d_in[0];
    const float* edge   = (const float*)d_in[1];
    const float* graph  = (const float*)d_in[2];
    const float* adj    = (const float*)d_in[3];
    const float* hidden = (const float*)d_in[4];
    const float* Wm1 = (const float*)d_in[5];  const float* bm1 = (const float*)d_in[6];
    const float* Wm2 = (const float*)d_in[7];  const float* bm2 = (const float*)d_in[8];
    const float* Wme = (const float*)d_in[9];  const float* bme = (const float*)d_in[10];
    const float* Wmg = (const float*)d_in[11]; const float* bmg = (const float*)d_in[12];
    const float* Wo1 = (const float*)d_in[13]; const float* bo1 = (const float*)d_in[14];
    const float* Wo2 = (const float*)d_in[15]; const float* bo2 = (const float*)d_in[16];
    const float* Wt1 = (const float*)d_in[17]; const float* bt1 = (const float*)d_in[18];
    const float* Wt2 = (const float*)d_in[19]; const float* bt2 = (const float*)d_in[20];
    const float* Wte = (const float*)d_in[21]; const float* bte = (const float*)d_in[22];
    const float* Wtg = (const float*)d_in[23]; const float* btg = (const float*)d_in[24];
    float* out = (float*)d_out;
    char* ws = (char*)d_ws;

    k0_precompute<<<dim3(513), dim3(256), 0, stream>>>(
        node, hidden, graph, Wm1, Wm2, Wo1, Wmg, Wt1, Wt2, Wtg, Wme, Wte,
        bm1, bm2, bme, bmg, bo1, bo2, bt1, bt2, bte, btg, ws);
    k2_main<<<dim3(32, 8, 2), dim3(512), 0, stream>>>(edge, adj, ws, out);
    k3_final<<<dim3(1024), dim3(128), 0, stream>>>(ws, Wo2, out);
}

// Round 6
// 472.512 us; speedup vs baseline: 1.0683x; 1.0598x over previous
//
#include <hip/hip_runtime.h>
#include <hip/hip_bf16.h>

// Problem constants
#define NB 2
#define NN 512
#define HH 128
#define DD 128
#define TT 8

// ws layout (bytes).
#define WPACK_OFF 0        // ushort[16*144*8] = 36864 B, bf16 [k/8][n][k%8]
#define C_OFF     36864    // float[2*512*128]  z@Wm1 + g@Wmg + (bm1+bm2+bme+bmg)
#define BROW_OFF  561152   // float[2*512*128]  z@Wm2
#define TC_OFF    1085440  // float[2*512*8]    z@Wt1 + g@Wtg + (bt1+bt2+bte+btg)
#define TB_OFF    1118208  // float[2*512*8]    z@Wt2
#define OC_OFF    1150976  // float[2*512*128]  z@Wo1 + bo1 + bo2
#define PART_OFF  1675264  // float[2*16*512*128] partial max (no C) per 32-sender chunk
#define ZF_OFF    10063872 // int[2*16*512]     1 if any sender in chunk has adj==0

#define OUT_TRI   131072   // float offset of tri_msgs in d_out

#define AP 132             // LDS A-row stride in floats (128 + 4 pad)

typedef float f32x4 __attribute__((ext_vector_type(4)));
typedef short s16x8 __attribute__((ext_vector_type(8)));

__device__ __forceinline__ unsigned short f2bf(float f) {
    union { float f; unsigned int u; } x; x.f = f;
    unsigned int u = x.u;
    unsigned int r = (u + 0x7FFFu + ((u >> 16) & 1u)) >> 16;  // RNE
    return (unsigned short)r;
}

// packed f32x2 -> bf16x2 (RNE). HW instr v_cvt_pk_bf16_f32 when available.
__device__ __forceinline__ unsigned cvt2bf(float a, float b) {
#if __has_builtin(__builtin_amdgcn_cvt_pk_bf16_f32)
    auto r = __builtin_amdgcn_cvt_pk_bf16_f32(a, b);
    return __builtin_bit_cast(unsigned, r);
#else
    return (unsigned)f2bf(a) | ((unsigned)f2bf(b) << 16);
#endif
}

// ---------------------------------------------------------------------------
// k0: precompute small projections (fp32) + pack bf16 weights for MFMA
// grid 513 x 256: blocks 0..511 handle 2 rows each; block 512 packs weights.
// ---------------------------------------------------------------------------
__global__ __launch_bounds__(256) void k0_precompute(
    const float* __restrict__ node, const float* __restrict__ hidden,
    const float* __restrict__ graph,
    const float* __restrict__ Wm1, const float* __restrict__ Wm2,
    const float* __restrict__ Wo1, const float* __restrict__ Wmg,
    const float* __restrict__ Wt1, const float* __restrict__ Wt2,
    const float* __restrict__ Wtg,
    const float* __restrict__ Wme, const float* __restrict__ Wte,
    const float* __restrict__ bm1, const float* __restrict__ bm2,
    const float* __restrict__ bme, const float* __restrict__ bmg,
    const float* __restrict__ bo1, const float* __restrict__ bo2,
    const float* __restrict__ bt1, const float* __restrict__ bt2,
    const float* __restrict__ bte, const float* __restrict__ btg,
    char* __restrict__ ws)
{
    const int bx = blockIdx.x, tid = threadIdx.x;
    if (bx == 512) {
        unsigned short* wp = (unsigned short*)(ws + WPACK_OFF);
        for (int idx = tid; idx < 16 * 144 * 8; idx += 256) {
            int j = idx & 7, tmp = idx >> 3;
            int n = tmp % 144, kq = tmp / 144;
            int k = kq * 8 + j;
            float v = 0.f;
            if (n < 128) v = Wme[k * 128 + n];
            else if (n < 136) v = Wte[k * 8 + (n - 128)];
            wp[idx] = f2bf(v);
        }
        return;
    }
    __shared__ float zs[2 * 260];
    const int row0 = bx * 2;       // flat row = b*512 + n
    const int b = row0 >> 9;
    #pragma unroll
    for (int e = 0; e < 2; e++) {
        int idx = e * 256 + tid;
        int rl = idx >> 8, col = idx & 255;
        float v = (col < 128) ? node[(row0 + rl) * 128 + col]
                              : hidden[(row0 + rl) * 128 + col - 128];
        zs[rl * 260 + col] = v;
    }
    __syncthreads();

    float* Cws = (float*)(ws + C_OFF);
    float* Bws = (float*)(ws + BROW_OFF);
    float* Ows = (float*)(ws + OC_OFF);
    float* TCw = (float*)(ws + TC_OFF);
    float* TBw = (float*)(ws + TB_OFF);

    const int d = tid & 127, half = tid >> 7;
    const int row = row0 + half;
    const float* z = zs + half * 260;
    float c = 0.f, q = 0.f, o = 0.f;
    #pragma unroll 8
    for (int k = 0; k < 256; k++) {
        float za = z[k];
        c = fmaf(za, Wm1[k * 128 + d], c);
        q = fmaf(za, Wm2[k * 128 + d], q);
        o = fmaf(za, Wo1[k * 128 + d], o);
    }
    float gm = 0.f;
    #pragma unroll 8
    for (int k = 0; k < 128; k++) gm = fmaf(graph[b * 128 + k], Wmg[k * 128 + d], gm);
    const float cb = gm + bm1[d] + bm2[d] + bme[d] + bmg[d];
    Cws[row * 128 + d] = c + cb;
    Bws[row * 128 + d] = q;
    Ows[row * 128 + d] = o + bo1[d] + bo2[d];

    if (tid < 32) {
        int rl = tid >> 4, t = (tid >> 1) & 7, which = tid & 1;
        const float* zr = zs + rl * 260;
        const float* W = which ? Wt2 : Wt1;
        float acc = 0.f;
        #pragma unroll 8
        for (int k = 0; k < 256; k++) acc = fmaf(zr[k], W[k * 8 + t], acc);
        int rg = row0 + rl;
        if (which == 0) {
            float gt = 0.f;
            #pragma unroll 8
            for (int k = 0; k < 128; k++) gt = fmaf(graph[b * 128 + k], Wtg[k * 8 + t], gt);
            TCw[rg * 8 + t] = acc + gt + bt1[t] + bt2[t] + bte[t] + btg[t];
        } else {
            TBw[rg * 8 + t] = acc;
        }
    }
}

// ---------------------------------------------------------------------------
// k2: fused edge GEMM + tri + masked max. A staged through double-buffered
// LDS (8KB/sender, cooperative); each of the 4 waves owns 2 disjoint D-column
// tiles (32 cols) + the rotating tri tile (sender ii -> wave ii&3).
// VGPR <= 128 -> 4 waves/SIMD, 4 blocks/CU (16 waves/CU) — r3-r5 were pinned
// at 2 waves/SIMD by a ~230-VGPR register budget and pure latency stall.
// No cross-wave reduce: waves own disjoint output columns.
// grid (32 jt, 16 ic, 2 b) = 1024 blocks x 256 thr (4 waves).
// ---------------------------------------------------------------------------
__global__ __launch_bounds__(256, 4) void k2_main(
    const float* __restrict__ edge, const float* __restrict__ adj,
    char* __restrict__ ws, float* __restrict__ out)
{
    __shared__ __align__(16) float As[2][16 * AP];   // 2 x 8448 B
    const int tid = threadIdx.x;
    const int jt = blockIdx.x, ic = blockIdx.y, b = blockIdx.z;
    const int j0 = jt * 16, i0 = ic * 32;

    const int lane = tid & 63, wave = tid >> 6;
    const int quad = lane >> 4, l15 = lane & 15;

    const float* Bws = (const float*)(ws + BROW_OFF);
    const float* TCw = (const float*)(ws + TC_OFF);
    const float* TBw = (const float*)(ws + TB_OFF);
    const s16x8* wp8 = (const s16x8*)(ws + WPACK_OFF);
    float* part = (float*)(ws + PART_OFF);
    int* Zws = (int*)(ws + ZF_OFF);

    // B fragments: 2 D tiles (cols (2*wave+ntl)*16+l15) + tri tile (cols 128+)
    s16x8 Bf[2][4], Bt[4];
    #pragma unroll
    for (int s = 0; s < 4; s++) {
        Bf[0][s] = wp8[(4 * s + quad) * 144 + (2 * wave) * 16 + l15];
        Bf[1][s] = wp8[(4 * s + quad) * 144 + (2 * wave + 1) * 16 + l15];
        Bt[s]    = wp8[(4 * s + quad) * 144 + 128 + l15];
    }

    const int jb = j0 + quad * 4;
    float TCf[4];
    #pragma unroll
    for (int r = 0; r < 4; r++)
        TCf[r] = (l15 < 8) ? TCw[(b * 512 + jb + r) * 8 + l15] : 0.f;

    // staging addressing: two float4 chunks per thread per sender
    const int f0 = tid, f1 = tid + 256;
    const int g0off = (f0 >> 5) * 128 + (f0 & 31) * 4;
    const int g1off = (f1 >> 5) * 128 + (f1 & 31) * 4;
    const int l0off = (f0 >> 5) * AP + (f0 & 31) * 4;
    const int l1off = (f1 >> 5) * AP + (f1 & 31) * 4;

    const size_t ebase = ((size_t)(b * 512 + i0) * 512 + j0) * 128;
    {   // prologue: sender i0 -> buf 0
        const float* nb = edge + ebase;
        *(float4*)&As[0][l0off] = *(const float4*)(nb + g0off);
        *(float4*)&As[0][l1off] = *(const float4*)(nb + g1off);
    }
    __syncthreads();

    float Mx[2][4];
    #pragma unroll
    for (int ntl = 0; ntl < 2; ntl++)
        #pragma unroll
        for (int r = 0; r < 4; r++) Mx[ntl][r] = -INFINITY;
    int anyz[4] = {0, 0, 0, 0};

    const int c0 = (2 * wave) * 16 + l15, c1 = c0 + 16;

    for (int ii = 0; ii < 32; ii++) {
        const int p = ii & 1, pn = p ^ 1;
        const int ig = i0 + ii;
        const int rowb = b * 512 + ig;

        // 1. issue next sender's A loads (consumed at ds_write below)
        float4 st0, st1;
        if (ii < 31) {
            const float* nb = edge + ebase + (size_t)(ii + 1) * 65536;
            st0 = *(const float4*)(nb + g0off);
            st1 = *(const float4*)(nb + g1off);
        }
        // 2. this sender's small operands (younger than st -> no forced drain)
        const float4 adjv = *(const float4*)(adj + (size_t)rowb * 512 + jb);
        const float brw0 = Bws[rowb * 128 + c0];
        const float brw1 = Bws[rowb * 128 + c1];
        const float tb   = TBw[rowb * 8 + (l15 & 7)];

        // 3. A fragments from LDS + cvt
        s16x8 af[4];
        const float* ap = &As[p][l15 * AP + quad * 8];
        #pragma unroll
        for (int s = 0; s < 4; s++) {
            float4 pv = *(const float4*)(ap + s * 32);
            float4 qv = *(const float4*)(ap + s * 32 + 4);
            union { s16x8 v; unsigned u[4]; } pk;
            pk.u[0] = cvt2bf(pv.x, pv.y);
            pk.u[1] = cvt2bf(pv.z, pv.w);
            pk.u[2] = cvt2bf(qv.x, qv.y);
            pk.u[3] = cvt2bf(qv.z, qv.w);
            af[s] = pk.v;
        }

        // 4. MFMA: 2 D tiles always; tri tile when it's my turn
        f32x4 acc0 = (f32x4){0.f, 0.f, 0.f, 0.f};
        f32x4 acc1 = (f32x4){0.f, 0.f, 0.f, 0.f};
        #pragma unroll
        for (int s = 0; s < 4; s++) {
            acc0 = __builtin_amdgcn_mfma_f32_16x16x32_bf16(af[s], Bf[0][s], acc0, 0, 0, 0);
            acc1 = __builtin_amdgcn_mfma_f32_16x16x32_bf16(af[s], Bf[1][s], acc1, 0, 0, 0);
        }
        const int trimine = ((ii & 3) == wave);
        f32x4 acct = (f32x4){0.f, 0.f, 0.f, 0.f};
        if (trimine) {
            #pragma unroll
            for (int s = 0; s < 4; s++)
                acct = __builtin_amdgcn_mfma_f32_16x16x32_bf16(af[s], Bt[s], acct, 0, 0, 0);
        }

        // 5. write next tile to the other LDS buffer (waits on st loads)
        if (ii < 31) {
            *(float4*)&As[pn][l0off] = st0;
            *(float4*)&As[pn][l1off] = st1;
        }

        // 6. masked-max epilogue (C deferred to k3)
        const float av[4] = {adjv.x, adjv.y, adjv.z, adjv.w};
        #pragma unroll
        for (int r = 0; r < 4; r++) {
            const int isz = (av[r] == 0.f);
            anyz[r] |= isz;
            Mx[0][r] = fmaxf(Mx[0][r], isz ? -INFINITY : (acc0[r] + brw0));
            Mx[1][r] = fmaxf(Mx[1][r], isz ? -INFINITY : (acc1[r] + brw1));
        }
        // 7. tri relu-store on my turn
        if (trimine && l15 < 8) {
            float* tout = out + OUT_TRI + ((size_t)rowb * 512 + jb) * 8 + l15;
            #pragma unroll
            for (int r = 0; r < 4; r++)
                tout[r * 8] = fmaxf(acct[r] + TCf[r] + tb, 0.f);
        }
        __syncthreads();
    }

    // store per-chunk partial max — waves own disjoint columns, no reduce
    #pragma unroll
    for (int r = 0; r < 4; r++) {
        const size_t pb = ((size_t)(b * 16 + ic) * 512 + jb + r) * 128;
        part[pb + c0] = Mx[0][r];
        part[pb + c1] = Mx[1][r];
    }
    if (wave == 0 && l15 == 0) {
        #pragma unroll
        for (int r = 0; r < 4; r++)
            Zws[(b * 16 + ic) * 512 + jb + r] = anyz[r];
    }
}

// ---------------------------------------------------------------------------
// k3: msgs = max(max_ic partial + C, anyzero?0:-inf); ret = Oc + msgs @ Wo2
// ---------------------------------------------------------------------------
__global__ __launch_bounds__(128) void k3_final(
    const char* __restrict__ ws, const float* __restrict__ Wo2,
    float* __restrict__ out)
{
    __shared__ float ms[128];
    const int bj = blockIdx.x, d = threadIdx.x;
    const int b = bj >> 9, j = bj & 511;
    const float* part = (const float*)(ws + PART_OFF);
    const int* Zws = (const int*)(ws + ZF_OFF);
    const float* Cws = (const float*)(ws + C_OFF);
    const float* Ows = (const float*)(ws + OC_OFF);

    const int rj = b * 512 + j;
    float m = -INFINITY;
    int zf = 0;
    #pragma unroll
    for (int ic = 0; ic < 16; ic++) {
        m = fmaxf(m, part[((size_t)(b * 16 + ic) * 512 + j) * 128 + d]);
        zf |= Zws[(b * 16 + ic) * 512 + j];
    }
    float c = Cws[rj * 128 + d];
    float mm = fmaxf(m + c, zf ? 0.f : -INFINITY);
    ms[d] = mm;
    __syncthreads();
    float acc = Ows[rj * 128 + d];
    #pragma unroll 8
    for (int k = 0; k < 128; k++) acc = fmaf(ms[k], Wo2[k * 128 + d], acc);
    out[rj * 128 + d] = acc;
}

extern "C" void kernel_launch(void* const* d_in, const int* in_sizes, int n_in,
                              void* d_out, int out_size, void* d_ws, size_t ws_size,
                              hipStream_t stream) {
    const float* node   = (const float*)d_in[0];
    const float* edge   = (const float*)d_in[1];
    const float* graph  = (const float*)d_in[2];
    const float* adj    = (const float*)d_in[3];
    const float* hidden = (const float*)d_in[4];
    const float* Wm1 = (const float*)d_in[5];  const float* bm1 = (const float*)d_in[6];
    const float* Wm2 = (const float*)d_in[7];  const float* bm2 = (const float*)d_in[8];
    const float* Wme = (const float*)d_in[9];  const float* bme = (const float*)d_in[10];
    const float* Wmg = (const float*)d_in[11]; const float* bmg = (const float*)d_in[12];
    const float* Wo1 = (const float*)d_in[13]; const float* bo1 = (const float*)d_in[14];
    const float* Wo2 = (const float*)d_in[15]; const float* bo2 = (const float*)d_in[16];
    const float* Wt1 = (const float*)d_in[17]; const float* bt1 = (const float*)d_in[18];
    const float* Wt2 = (const float*)d_in[19]; const float* bt2 = (const float*)d_in[20];
    const float* Wte = (const float*)d_in[21]; const float* bte = (const float*)d_in[22];
    const float* Wtg = (const float*)d_in[23]; const float* btg = (const float*)d_in[24];
    float* out = (float*)d_out;
    char* ws = (char*)d_ws;

    k0_precompute<<<dim3(513), dim3(256), 0, stream>>>(
        node, hidden, graph, Wm1, Wm2, Wo1, Wmg, Wt1, Wt2, Wtg, Wme, Wte,
        bm1, bm2, bme, bmg, bo1, bo2, bt1, bt2, bte, btg, ws);
    k2_main<<<dim3(32, 16, 2), dim3(256), 0, stream>>>(edge, adj, ws, out);
    k3_final<<<dim3(1024), dim3(128), 0, stream>>>(ws, Wo2, out);
}